// Round 23
// baseline (142.085 us; speedup 1.0000x reference)
//
#include <hip/hip_runtime.h>
#include <math.h>

#define N_ROWS 32768
#define DIM 256
#define K_CODES 1024
#define MARGIN 2e-3f

typedef float f32x4v __attribute__((ext_vector_type(4)));
typedef short s16x8 __attribute__((ext_vector_type(8)));

// ---- ws layout (bytes) ----
// flaglist int[32768]       @ 0        (fallback uses as x2 floats)
// w2       float[1024]      @ 131072
// wfrag    ushort[524288]   @ 135168   (64 tiles x 16KB, fragment-major)
// flagcnt  int              @ 1183744
#define WS_NEEDED ((size_t)1183748)

__device__ __forceinline__ unsigned short bf16_rne(float f) {
    unsigned int u = __float_as_uint(f);
    unsigned int r = (u + 0x7FFFu + ((u >> 16) & 1u)) >> 16;
    return (unsigned short)r;
}
__device__ __forceinline__ float bf16_f32(unsigned short h) {
    return __uint_as_float(((unsigned int)h) << 16);
}

// ---------------------------------------------------------------------------
// numpy-replica pairwise sum of squares (AVX512 path) — bitwise == np.sum(x*x)
// ---------------------------------------------------------------------------
__device__ __forceinline__ float np_block128_sumsq(const float* e) {
#pragma clang fp contract(off)
    float s[16];
#pragma unroll
    for (int l = 0; l < 16; ++l) {
        float a0 = e[l]       * e[l];
        float a1 = e[16 + l]  * e[16 + l];
        float a2 = e[32 + l]  * e[32 + l];
        float a3 = e[48 + l]  * e[48 + l];
        float a4 = e[64 + l]  * e[64 + l];
        float a5 = e[80 + l]  * e[80 + l];
        float a6 = e[96 + l]  * e[96 + l];
        float a7 = e[112 + l] * e[112 + l];
        s[l] = ((a0 + a1) + (a2 + a3)) + ((a4 + a5) + (a6 + a7));
    }
    float t1[8];
#pragma unroll
    for (int i = 0; i < 8; ++i) t1[i] = s[i] + s[i + 8];
    float t2[4];
#pragma unroll
    for (int i = 0; i < 4; ++i) t2[i] = t1[i] + t1[i + 4];
    return (t2[0] + t2[2]) + (t2[1] + t2[3]);
}

__global__ __launch_bounds__(64) void npsumsq_kernel(const float* __restrict__ src,
                                                     float* __restrict__ dst) {
    __shared__ float buf[16][257];
    const int tid = threadIdx.x;
    const int r0 = blockIdx.x * 16;
#pragma unroll
    for (int it = 0; it < 16; ++it) {
        int idx = it * 64 + tid;
        int r = idx >> 6, c4 = idx & 63;
        float4 v = ((const float4*)(src + (size_t)(r0 + r) * DIM))[c4];
        buf[r][c4 * 4 + 0] = v.x;
        buf[r][c4 * 4 + 1] = v.y;
        buf[r][c4 * 4 + 2] = v.z;
        buf[r][c4 * 4 + 3] = v.w;
    }
    __syncthreads();
    if (tid < 16) {
        const float* e = buf[tid];
        dst[r0 + tid] = np_block128_sumsq(e) + np_block128_sumsq(e + 128);
    }
}

// ---------------------------------------------------------------------------
// wprep (256 thr/tile): per 16-code tile, w2 (np tree) + bf16 hi/lo splits in
// FRAGMENT-MAJOR layout (tile = 16384 B; hi frag bytes q*1024 + lane*16; lo
// at +8192 B). Sub-wave sw handles q = 2*sw, 2*sw+1. Block 0 zeroes flagcnt.
// ---------------------------------------------------------------------------
__global__ __launch_bounds__(256) void wprep_kernel(const float* __restrict__ w,
                                                    float* __restrict__ w2,
                                                    unsigned short* __restrict__ wfrag,
                                                    int* __restrict__ flagcnt) {
    __shared__ float buf[16][257];
    const int tid = threadIdx.x;
    const int lane = tid & 63;
    const int sw = tid >> 6;          // 0..3
    const int t = blockIdx.x;
    const int r0 = t * 16;
    if (t == 0 && tid == 0) flagcnt[0] = 0;
#pragma unroll
    for (int it = 0; it < 4; ++it) {
        int idx = it * 256 + tid;     // 1024 float4 total
        int r = idx >> 6, c4 = idx & 63;
        float4 v = ((const float4*)(w + (size_t)(r0 + r) * DIM))[c4];
        buf[r][c4 * 4 + 0] = v.x;
        buf[r][c4 * 4 + 1] = v.y;
        buf[r][c4 * 4 + 2] = v.z;
        buf[r][c4 * 4 + 3] = v.w;
    }
    __syncthreads();
    if (tid < 16) {
        const float* e = buf[tid];
        w2[r0 + tid] = np_block128_sumsq(e) + np_block128_sumsq(e + 128);
    }
    const int c = lane & 15, ko = lane >> 4;
#pragma unroll
    for (int qq = 0; qq < 2; ++qq) {
        const int q = sw * 2 + qq;
        s16x8 hh, ll;
#pragma unroll
        for (int i = 0; i < 8; ++i) {
            float f = buf[c][q * 32 + ko * 8 + i];
            unsigned short h = bf16_rne(f);
            hh[i] = (short)h;
            ll[i] = (short)bf16_rne(f - bf16_f32(h));
        }
        unsigned short* dh = wfrag + (size_t)t * 8192 + q * 512 + lane * 8;
        *(s16x8*)dh = hh;
        *(s16x8*)(dh + 4096) = ll;
    }
}

// ---------------------------------------------------------------------------
// Main: r22's verified 83us structure with ONE change: staging via
// __builtin_amdgcn_global_load_lds (width 16) instead of global->reg->ds_write.
// Dest is linear per wave (base tiles[buf][wave*64+s*256] + lane*16B), which
// is exactly the wave-uniform-base+lane*size pattern the DMA requires (m104).
// Removes 32 ds_write_b128/CU-ct from the saturated LDS pipe + 16 prefetch
// VGPRs; the async DMA overlaps the MFMA phase and drains at the barrier.
// ---------------------------------------------------------------------------
__global__ __launch_bounds__(256, 2) void vq_mfma(
    const float* __restrict__ x, const uint4* __restrict__ wfrag4,
    const float* __restrict__ w2g, const float* __restrict__ w,
    float* __restrict__ zout, float* __restrict__ zq,
    int* __restrict__ flagcnt, int* __restrict__ flaglist) {
    __shared__ uint4 tiles[2][1024];   // 2 x 16KB
    __shared__ float sw2[K_CODES];
    __shared__ int widx_s[64];

    const int tid = threadIdx.x;
    const int wave = tid >> 6;        // 0..3
    const int lane = tid & 63;
    const int rowblk = blockIdx.x * 64;
    const int rowbase = rowblk + wave * 16;

    for (int i = tid; i < K_CODES; i += 256) sw2[i] = w2g[i];

    // ---- A fragments: inline f32 -> bf16 hi/lo split (16 rows per wave) ----
    s16x8 ahi[8], alo[8];
    {
        const float* xr = x + (size_t)(rowbase + (lane & 15)) * DIM + (lane >> 4) * 8;
#pragma unroll
        for (int q = 0; q < 8; ++q) {
            float4 a = *(const float4*)(xr + q * 32);
            float4 b = *(const float4*)(xr + q * 32 + 4);
            float e[8] = {a.x, a.y, a.z, a.w, b.x, b.y, b.z, b.w};
#pragma unroll
            for (int i = 0; i < 8; ++i) {
                unsigned short h = bf16_rne(e[i]);
                ahi[q][i] = (short)h;
                alo[q][i] = (short)bf16_rne(e[i] - bf16_f32(h));
            }
        }
    }

    // ---- async staging helper: wave-linear DMA of one tile quarter ----
    // instruction s of wave w: lds dest = tiles[buf][w*64 + s*256] + lane*16B,
    // global src = wfrag4[ct*1024 + s*256 + w*64 + lane]  (per-lane address)
#define STAGE_TILE(BUF, CT)                                                     \
    {                                                                           \
        const uint4* gbase = wfrag4 + (size_t)(CT) * 1024;                      \
        _Pragma("unroll")                                                       \
        for (int s = 0; s < 4; ++s) {                                           \
            __builtin_amdgcn_global_load_lds(                                   \
                (const __attribute__((address_space(1))) unsigned int*)         \
                    (gbase + s * 256 + wave * 64 + lane),                       \
                (__attribute__((address_space(3))) unsigned int*)               \
                    (&tiles[BUF][wave * 64 + s * 256]),                         \
                16, 0, 0);                                                      \
        }                                                                       \
    }

    // ---- prologue: stage tile 0 ----
    STAGE_TILE(0, 0)

    float b1[4], b2[4];
    int i1[4];
#pragma unroll
    for (int j = 0; j < 4; ++j) { b1[j] = INFINITY; b2[j] = INFINITY; i1[j] = 0; }

    __syncthreads();   // drains the tile-0 DMA

    int cur = 0;
    for (int ct = 0; ct < 64; ++ct) {
        // issue async DMA for next tile (overlaps the MFMAs below)
        if (ct < 63) STAGE_TILE(cur ^ 1, ct + 1)
        const uint4* th = tiles[cur];
        f32x4v ahh = {0.f, 0.f, 0.f, 0.f};
        f32x4v ahl = {0.f, 0.f, 0.f, 0.f};
        f32x4v alh = {0.f, 0.f, 0.f, 0.f};
#pragma unroll
        for (int q = 0; q < 8; ++q) {
            s16x8 Bh = *(const s16x8*)&th[q * 64 + lane];
            s16x8 Bl = *(const s16x8*)&th[512 + q * 64 + lane];
            ahh = __builtin_amdgcn_mfma_f32_16x16x32_bf16(ahi[q], Bh, ahh, 0, 0, 0);
            ahl = __builtin_amdgcn_mfma_f32_16x16x32_bf16(ahi[q], Bl, ahl, 0, 0, 0);
            alh = __builtin_amdgcn_mfma_f32_16x16x32_bf16(alo[q], Bh, alh, 0, 0, 0);
        }
        const int code = ct * 16 + (lane & 15);
        const float w2v = sw2[code];
#pragma unroll
        for (int j = 0; j < 4; ++j) {
            float d = (ahh[j] + ahl[j]) + alh[j];
            float s = w2v - 2.0f * d;
            if (s < b2[j]) {
                if (s < b1[j]) { b2[j] = b1[j]; b1[j] = s; i1[j] = code; }
                else b2[j] = s;
            }
        }
        __syncthreads();   // drains DMA: tiles[cur^1] ready for next iter
        cur ^= 1;
    }

    // butterfly top-2 reduce across the 16-lane code group (masks 1,2,4,8)
#pragma unroll
    for (int m = 1; m < 16; m <<= 1) {
#pragma unroll
        for (int j = 0; j < 4; ++j) {
            float ov1 = __shfl_xor(b1[j], m);
            int oi = __shfl_xor(i1[j], m);
            float ov2 = __shfl_xor(b2[j], m);
            float nb2 = fminf(fmaxf(b1[j], ov1), fminf(b2[j], ov2));
            if (ov1 < b1[j] || (ov1 == b1[j] && oi < i1[j])) { b1[j] = ov1; i1[j] = oi; }
            b2[j] = nb2;
        }
    }
    if ((lane & 15) == 0) {
#pragma unroll
        for (int j = 0; j < 4; ++j) {
            int rl = wave * 16 + (lane >> 4) * 4 + j;
            widx_s[rl] = i1[j];
            zout[rowblk + rl] = (float)i1[j];
            if (b2[j] - b1[j] < MARGIN) {
                int slot = atomicAdd(flagcnt, 1);
                flaglist[slot] = rowblk + rl;
            }
        }
    }
    __syncthreads();

    // fused gather: 64 rows x 64 float4 = 4096 / 256 threads
    const float4* w4 = (const float4*)w;
    float4* zq4 = (float4*)zq;
#pragma unroll
    for (int p = 0; p < 16; ++p) {
        int lin = p * 256 + tid;
        int row = lin >> 6, qq = lin & 63;
        zq4[(size_t)(rowblk + row) * 64 + qq] = w4[(size_t)widx_s[row] * 64 + qq];
    }
#undef STAGE_TILE
}

// ---------------------------------------------------------------------------
// Exact np-f32 rescore of compacted flagged rows (round-5-verified semantics;
// k4-outer/cc-inner, no spill — round 10/11 lesson).
// ---------------------------------------------------------------------------
__global__ __launch_bounds__(256) void rescue_kernel(
    const float* __restrict__ x, const float* __restrict__ w,
    const float* __restrict__ w2g, const int* __restrict__ flagcnt,
    const int* __restrict__ flaglist, float* __restrict__ zout,
    float* __restrict__ zq) {
    __shared__ __align__(16) float xs[DIM];
    __shared__ float dv[256];
    __shared__ int di[256];
    __shared__ int mi_s;
    __shared__ float x2_s;
    const int tid = threadIdx.x;
    const int cnt = flagcnt[0];
    for (int f = blockIdx.x; f < cnt; f += gridDim.x) {
        const int r = flaglist[f];
        __syncthreads();
        for (int i = tid; i < DIM; i += 256) xs[i] = x[(size_t)r * DIM + i];
        __syncthreads();
        if (tid == 0)
            x2_s = np_block128_sumsq(xs) + np_block128_sumsq(xs + 128);
        __syncthreads();
        const float x2vv = x2_s;
        const float4* xs4 = (const float4*)xs;
        const float4* wr0 = (const float4*)(w + (size_t)(tid + 0 * 256) * DIM);
        const float4* wr1 = (const float4*)(w + (size_t)(tid + 1 * 256) * DIM);
        const float4* wr2 = (const float4*)(w + (size_t)(tid + 2 * 256) * DIM);
        const float4* wr3 = (const float4*)(w + (size_t)(tid + 3 * 256) * DIM);
        float acc0 = 0.f, acc1 = 0.f, acc2 = 0.f, acc3 = 0.f;
#pragma unroll 4
        for (int k4 = 0; k4 < DIM / 4; ++k4) {
            float4 xv = xs4[k4];
            float4 w0 = wr0[k4], w1 = wr1[k4], w2 = wr2[k4], w3 = wr3[k4];
            acc0 = __builtin_fmaf(xv.x, w0.x, acc0);
            acc0 = __builtin_fmaf(xv.y, w0.y, acc0);
            acc0 = __builtin_fmaf(xv.z, w0.z, acc0);
            acc0 = __builtin_fmaf(xv.w, w0.w, acc0);
            acc1 = __builtin_fmaf(xv.x, w1.x, acc1);
            acc1 = __builtin_fmaf(xv.y, w1.y, acc1);
            acc1 = __builtin_fmaf(xv.z, w1.z, acc1);
            acc1 = __builtin_fmaf(xv.w, w1.w, acc1);
            acc2 = __builtin_fmaf(xv.x, w2.x, acc2);
            acc2 = __builtin_fmaf(xv.y, w2.y, acc2);
            acc2 = __builtin_fmaf(xv.z, w2.z, acc2);
            acc2 = __builtin_fmaf(xv.w, w2.w, acc2);
            acc3 = __builtin_fmaf(xv.x, w3.x, acc3);
            acc3 = __builtin_fmaf(xv.y, w3.y, acc3);
            acc3 = __builtin_fmaf(xv.z, w3.z, acc3);
            acc3 = __builtin_fmaf(xv.w, w3.w, acc3);
        }
        float bv = INFINITY;
        int bi = 0;
        float accs[4] = {acc0, acc1, acc2, acc3};
#pragma unroll
        for (int cc = 0; cc < 4; ++cc) {
            int c = tid + cc * 256;
            float s = (x2vv - 2.0f * accs[cc]) + w2g[c];
            if (s < bv) { bv = s; bi = c; }
        }
        dv[tid] = bv;
        di[tid] = bi;
        __syncthreads();
        if (tid == 0) {
            float mv = dv[0];
            int mi = di[0];
            for (int t = 1; t < 256; ++t)
                if (dv[t] < mv || (dv[t] == mv && di[t] < mi)) { mv = dv[t]; mi = di[t]; }
            zout[r] = (float)mi;
            mi_s = mi;
        }
        __syncthreads();
        zq[(size_t)r * DIM + tid] = w[(size_t)mi_s * DIM + tid];
    }
}

// ===========================================================================
// Fallback (round-5 passing LDS kernel) if ws is too small. Needs only x2/w2.
// ===========================================================================
#define BM 64
#define BN 128
#define BK 64
#define LDX 68

__global__ __launch_bounds__(256) void vq_kernel_lds(
    const float* __restrict__ x, const float* __restrict__ w,
    const float* __restrict__ x2g, const float* __restrict__ w2g,
    float* __restrict__ zout, float* __restrict__ zq) {
    __shared__ float xs[BM * LDX];
    __shared__ float ws_[BN * LDX];
    __shared__ float sw2[K_CODES];
    __shared__ float sx2[BM];
    __shared__ int widx[BM];

    const int tid = threadIdx.x;
    const int bm0 = blockIdx.x * BM;
    const int rg = tid & 15;
    const int cg = tid >> 4;

    for (int i = tid; i < K_CODES; i += 256) sw2[i] = w2g[i];
    if (tid < BM) sx2[tid] = x2g[bm0 + tid];

    float best[4];
    int bidx[4];
#pragma unroll
    for (int i = 0; i < 4; ++i) { best[i] = INFINITY; bidx[i] = 0; }

    const float4* x4 = (const float4*)x;
    const float4* w4 = (const float4*)w;

    for (int cn = 0; cn < K_CODES / BN; ++cn) {
        float acc[4][8];
#pragma unroll
        for (int i = 0; i < 4; ++i)
#pragma unroll
            for (int j = 0; j < 8; ++j) acc[i][j] = 0.f;

        for (int dk = 0; dk < DIM / BK; ++dk) {
            __syncthreads();
#pragma unroll
            for (int p = 0; p < 4; ++p) {
                int l = p * 256 + tid;
                int row = l >> 4, c4 = l & 15;
                float4 v = x4[(size_t)(bm0 + row) * (DIM / 4) + dk * (BK / 4) + c4];
                *(float4*)&xs[row * LDX + c4 * 4] = v;
            }
#pragma unroll
            for (int p = 0; p < 8; ++p) {
                int l = p * 256 + tid;
                int row = l >> 4, c4 = l & 15;
                float4 v = w4[(size_t)(cn * BN + row) * (DIM / 4) + dk * (BK / 4) + c4];
                *(float4*)&ws_[row * LDX + c4 * 4] = v;
            }
            __syncthreads();
#pragma unroll
            for (int d = 0; d < BK; d += 4) {
                float4 xv[4], wv[8];
#pragma unroll
                for (int i = 0; i < 4; ++i)
                    xv[i] = *(const float4*)&xs[(rg + 16 * i) * LDX + d];
#pragma unroll
                for (int j = 0; j < 8; ++j)
                    wv[j] = *(const float4*)&ws_[(cg + 16 * j) * LDX + d];
#pragma unroll
                for (int i = 0; i < 4; ++i)
#pragma unroll
                    for (int j = 0; j < 8; ++j) {
                        acc[i][j] = __builtin_fmaf(xv[i].x, wv[j].x, acc[i][j]);
                        acc[i][j] = __builtin_fmaf(xv[i].y, wv[j].y, acc[i][j]);
                        acc[i][j] = __builtin_fmaf(xv[i].z, wv[j].z, acc[i][j]);
                        acc[i][j] = __builtin_fmaf(xv[i].w, wv[j].w, acc[i][j]);
                    }
            }
        }
#pragma unroll
        for (int j = 0; j < 8; ++j) {
            int c = cn * BN + cg + 16 * j;
            float w2v = sw2[c];
#pragma unroll
            for (int i = 0; i < 4; ++i) {
                float t = sx2[rg + 16 * i] - 2.0f * acc[i][j];
                float s = t + w2v;
                if (s < best[i]) { best[i] = s; bidx[i] = c; }
            }
        }
    }

    __syncthreads();
    float* sval = xs;
    int* sidx = (int*)(xs + 64 * 17);
#pragma unroll
    for (int i = 0; i < 4; ++i) {
        sval[(rg + 16 * i) * 17 + cg] = best[i];
        sidx[(rg + 16 * i) * 17 + cg] = bidx[i];
    }
    __syncthreads();
    if (tid < BM) {
        float bv = INFINITY;
        int bi = 0;
        for (int c = 0; c < 16; ++c) {
            float v = sval[tid * 17 + c];
            int id = sidx[tid * 17 + c];
            if (v < bv || (v == bv && id < bi)) { bv = v; bi = id; }
        }
        widx[tid] = bi;
        zout[bm0 + tid] = (float)bi;
    }
    __syncthreads();
    float4* zq4 = (float4*)zq;
#pragma unroll
    for (int p = 0; p < 16; ++p) {
        int lin = p * 256 + tid;
        int row = lin >> 6, q = lin & 63;
        zq4[(size_t)(bm0 + row) * 64 + q] = w4[(size_t)widx[row] * 64 + q];
    }
}

extern "C" void kernel_launch(void* const* d_in, const int* in_sizes, int n_in,
                              void* d_out, int out_size, void* d_ws, size_t ws_size,
                              hipStream_t stream) {
    const float* z_e = (const float*)d_in[0];
    const float* emb = (const float*)d_in[1];
    float* x2g = (float*)d_ws;                                   // fallback x2
    int* flaglist = (int*)d_ws;                                  // MFMA path [32768]
    float* w2g = x2g + N_ROWS;                                   // [1024]
    unsigned short* wfrag = (unsigned short*)(w2g + K_CODES);    // [524288] = 1 MB
    int* flagcnt = (int*)(wfrag + (size_t)2 * K_CODES * DIM);    // [1]
    float* zout = (float*)d_out;                                 // [32768]
    float* zq = (float*)d_out + N_ROWS;                          // [32768*256]

    if (ws_size >= WS_NEEDED) {
        wprep_kernel<<<K_CODES / 16, 256, 0, stream>>>(emb, w2g, wfrag, flagcnt);
        vq_mfma<<<N_ROWS / 64, 256, 0, stream>>>(z_e, (const uint4*)wfrag, w2g,
                                                 emb, zout, zq, flagcnt, flaglist);
        rescue_kernel<<<256, 256, 0, stream>>>(z_e, emb, w2g, flagcnt,
                                               flaglist, zout, zq);
    } else {
        npsumsq_kernel<<<N_ROWS / 16, 64, 0, stream>>>(z_e, x2g);
        npsumsq_kernel<<<K_CODES / 16, 64, 0, stream>>>(emb, w2g);
        vq_kernel_lds<<<N_ROWS / BM, 256, 0, stream>>>(z_e, emb, x2g, w2g, zout, zq);
    }
}

// Round 24
// 131.580 us; speedup vs baseline: 1.0798x; 1.0798x over previous
//
#include <hip/hip_runtime.h>
#include <math.h>

#define N_ROWS 32768
#define DIM 256
#define K_CODES 1024
#define MARGIN 2e-3f

typedef float f32x4v __attribute__((ext_vector_type(4)));
typedef short s16x8 __attribute__((ext_vector_type(8)));

// ---- ws layout (bytes) ----
// flaglist int[32768]       @ 0        (fallback uses as x2 floats)
// w2       float[1024]      @ 131072
// wfrag    ushort[524288]   @ 135168   (64 tiles x 16KB, fragment-major)
// flagcnt  int              @ 1183744
#define WS_NEEDED ((size_t)1183748)

__device__ __forceinline__ unsigned short bf16_rne(float f) {
    unsigned int u = __float_as_uint(f);
    unsigned int r = (u + 0x7FFFu + ((u >> 16) & 1u)) >> 16;
    return (unsigned short)r;
}
__device__ __forceinline__ float bf16_f32(unsigned short h) {
    return __uint_as_float(((unsigned int)h) << 16);
}

// ---------------------------------------------------------------------------
// numpy-replica pairwise sum of squares (AVX512 path) — bitwise == np.sum(x*x)
// ---------------------------------------------------------------------------
__device__ __forceinline__ float np_block128_sumsq(const float* e) {
#pragma clang fp contract(off)
    float s[16];
#pragma unroll
    for (int l = 0; l < 16; ++l) {
        float a0 = e[l]       * e[l];
        float a1 = e[16 + l]  * e[16 + l];
        float a2 = e[32 + l]  * e[32 + l];
        float a3 = e[48 + l]  * e[48 + l];
        float a4 = e[64 + l]  * e[64 + l];
        float a5 = e[80 + l]  * e[80 + l];
        float a6 = e[96 + l]  * e[96 + l];
        float a7 = e[112 + l] * e[112 + l];
        s[l] = ((a0 + a1) + (a2 + a3)) + ((a4 + a5) + (a6 + a7));
    }
    float t1[8];
#pragma unroll
    for (int i = 0; i < 8; ++i) t1[i] = s[i] + s[i + 8];
    float t2[4];
#pragma unroll
    for (int i = 0; i < 4; ++i) t2[i] = t1[i] + t1[i + 4];
    return (t2[0] + t2[2]) + (t2[1] + t2[3]);
}

__global__ __launch_bounds__(64) void npsumsq_kernel(const float* __restrict__ src,
                                                     float* __restrict__ dst) {
    __shared__ float buf[16][257];
    const int tid = threadIdx.x;
    const int r0 = blockIdx.x * 16;
#pragma unroll
    for (int it = 0; it < 16; ++it) {
        int idx = it * 64 + tid;
        int r = idx >> 6, c4 = idx & 63;
        float4 v = ((const float4*)(src + (size_t)(r0 + r) * DIM))[c4];
        buf[r][c4 * 4 + 0] = v.x;
        buf[r][c4 * 4 + 1] = v.y;
        buf[r][c4 * 4 + 2] = v.z;
        buf[r][c4 * 4 + 3] = v.w;
    }
    __syncthreads();
    if (tid < 16) {
        const float* e = buf[tid];
        dst[r0 + tid] = np_block128_sumsq(e) + np_block128_sumsq(e + 128);
    }
}

// ---------------------------------------------------------------------------
// wprep (256 thr/tile): per 16-code tile, w2 (np tree) + bf16 hi/lo splits in
// FRAGMENT-MAJOR layout (tile = 16384 B; hi frag bytes q*1024 + lane*16; lo
// at +8192 B). Sub-wave sw handles q = 2*sw, 2*sw+1. Block 0 zeroes flagcnt.
// ---------------------------------------------------------------------------
__global__ __launch_bounds__(256) void wprep_kernel(const float* __restrict__ w,
                                                    float* __restrict__ w2,
                                                    unsigned short* __restrict__ wfrag,
                                                    int* __restrict__ flagcnt) {
    __shared__ float buf[16][257];
    const int tid = threadIdx.x;
    const int lane = tid & 63;
    const int sw = tid >> 6;          // 0..3
    const int t = blockIdx.x;
    const int r0 = t * 16;
    if (t == 0 && tid == 0) flagcnt[0] = 0;
#pragma unroll
    for (int it = 0; it < 4; ++it) {
        int idx = it * 256 + tid;     // 1024 float4 total
        int r = idx >> 6, c4 = idx & 63;
        float4 v = ((const float4*)(w + (size_t)(r0 + r) * DIM))[c4];
        buf[r][c4 * 4 + 0] = v.x;
        buf[r][c4 * 4 + 1] = v.y;
        buf[r][c4 * 4 + 2] = v.z;
        buf[r][c4 * 4 + 3] = v.w;
    }
    __syncthreads();
    if (tid < 16) {
        const float* e = buf[tid];
        w2[r0 + tid] = np_block128_sumsq(e) + np_block128_sumsq(e + 128);
    }
    const int c = lane & 15, ko = lane >> 4;
#pragma unroll
    for (int qq = 0; qq < 2; ++qq) {
        const int q = sw * 2 + qq;
        s16x8 hh, ll;
#pragma unroll
        for (int i = 0; i < 8; ++i) {
            float f = buf[c][q * 32 + ko * 8 + i];
            unsigned short h = bf16_rne(f);
            hh[i] = (short)h;
            ll[i] = (short)bf16_rne(f - bf16_f32(h));
        }
        unsigned short* dh = wfrag + (size_t)t * 8192 + q * 512 + lane * 8;
        *(s16x8*)dh = hh;
        *(s16x8*)(dh + 4096) = ll;
    }
}

// ---------------------------------------------------------------------------
// Main (VERIFIED BEST — 83us, total 131.8us, round 22): block = 64 rows
// (4 waves x 16 rows, 256 thr), grid 512, 2 blk/CU. Double-buffered shared
// code tile via reg-staged prefetch; each wave owns its rows. 3-chain
// split-bf16 MFMA; score = w2 - 2*dot; margin flags to global list; fused
// gather. Seven structural variants (r12/15/17/18/19/20-21/23) all measured
// neutral-or-worse; keep this configuration.
// ---------------------------------------------------------------------------
__global__ __launch_bounds__(256, 2) void vq_mfma(
    const float* __restrict__ x, const uint4* __restrict__ wfrag4,
    const float* __restrict__ w2g, const float* __restrict__ w,
    float* __restrict__ zout, float* __restrict__ zq,
    int* __restrict__ flagcnt, int* __restrict__ flaglist) {
    __shared__ uint4 tiles[2][1024];   // 2 x 16KB
    __shared__ float sw2[K_CODES];
    __shared__ int widx_s[64];

    const int tid = threadIdx.x;
    const int wave = tid >> 6;        // 0..3
    const int lane = tid & 63;
    const int rowblk = blockIdx.x * 64;
    const int rowbase = rowblk + wave * 16;

    for (int i = tid; i < K_CODES; i += 256) sw2[i] = w2g[i];

    // ---- A fragments: inline f32 -> bf16 hi/lo split (16 rows per wave) ----
    s16x8 ahi[8], alo[8];
    {
        const float* xr = x + (size_t)(rowbase + (lane & 15)) * DIM + (lane >> 4) * 8;
#pragma unroll
        for (int q = 0; q < 8; ++q) {
            float4 a = *(const float4*)(xr + q * 32);
            float4 b = *(const float4*)(xr + q * 32 + 4);
            float e[8] = {a.x, a.y, a.z, a.w, b.x, b.y, b.z, b.w};
#pragma unroll
            for (int i = 0; i < 8; ++i) {
                unsigned short h = bf16_rne(e[i]);
                ahi[q][i] = (short)h;
                alo[q][i] = (short)bf16_rne(e[i] - bf16_f32(h));
            }
        }
    }

    // ---- prologue: stage tile 0 (1024 uint4 / 256 threads) ----
    tiles[0][tid] = wfrag4[tid];
    tiles[0][tid + 256] = wfrag4[tid + 256];
    tiles[0][tid + 512] = wfrag4[tid + 512];
    tiles[0][tid + 768] = wfrag4[tid + 768];

    float b1[4], b2[4];
    int i1[4];
#pragma unroll
    for (int j = 0; j < 4; ++j) { b1[j] = INFINITY; b2[j] = INFINITY; i1[j] = 0; }

    __syncthreads();

    int cur = 0;
    for (int ct = 0; ct < 64; ++ct) {
        // prefetch next tile into regs (hidden under MFMAs)
        uint4 pf0, pf1, pf2, pf3;
        if (ct < 63) {
            const uint4* g = wfrag4 + (size_t)(ct + 1) * 1024;
            pf0 = g[tid];
            pf1 = g[tid + 256];
            pf2 = g[tid + 512];
            pf3 = g[tid + 768];
        }
        const uint4* th = tiles[cur];
        f32x4v ahh = {0.f, 0.f, 0.f, 0.f};
        f32x4v ahl = {0.f, 0.f, 0.f, 0.f};
        f32x4v alh = {0.f, 0.f, 0.f, 0.f};
#pragma unroll
        for (int q = 0; q < 8; ++q) {
            s16x8 Bh = *(const s16x8*)&th[q * 64 + lane];
            s16x8 Bl = *(const s16x8*)&th[512 + q * 64 + lane];
            ahh = __builtin_amdgcn_mfma_f32_16x16x32_bf16(ahi[q], Bh, ahh, 0, 0, 0);
            ahl = __builtin_amdgcn_mfma_f32_16x16x32_bf16(ahi[q], Bl, ahl, 0, 0, 0);
            alh = __builtin_amdgcn_mfma_f32_16x16x32_bf16(alo[q], Bh, alh, 0, 0, 0);
        }
        const int code = ct * 16 + (lane & 15);
        const float w2v = sw2[code];
#pragma unroll
        for (int j = 0; j < 4; ++j) {
            float d = (ahh[j] + ahl[j]) + alh[j];
            float s = w2v - 2.0f * d;
            if (s < b2[j]) {
                if (s < b1[j]) { b2[j] = b1[j]; b1[j] = s; i1[j] = code; }
                else b2[j] = s;
            }
        }
        if (ct < 63) {
            uint4* d = tiles[cur ^ 1];
            d[tid] = pf0;
            d[tid + 256] = pf1;
            d[tid + 512] = pf2;
            d[tid + 768] = pf3;
            cur ^= 1;
        }
        __syncthreads();
    }

    // butterfly top-2 reduce across the 16-lane code group (masks 1,2,4,8)
#pragma unroll
    for (int m = 1; m < 16; m <<= 1) {
#pragma unroll
        for (int j = 0; j < 4; ++j) {
            float ov1 = __shfl_xor(b1[j], m);
            int oi = __shfl_xor(i1[j], m);
            float ov2 = __shfl_xor(b2[j], m);
            float nb2 = fminf(fmaxf(b1[j], ov1), fminf(b2[j], ov2));
            if (ov1 < b1[j] || (ov1 == b1[j] && oi < i1[j])) { b1[j] = ov1; i1[j] = oi; }
            b2[j] = nb2;
        }
    }
    if ((lane & 15) == 0) {
#pragma unroll
        for (int j = 0; j < 4; ++j) {
            int rl = wave * 16 + (lane >> 4) * 4 + j;
            widx_s[rl] = i1[j];
            zout[rowblk + rl] = (float)i1[j];
            if (b2[j] - b1[j] < MARGIN) {
                int slot = atomicAdd(flagcnt, 1);
                flaglist[slot] = rowblk + rl;
            }
        }
    }
    __syncthreads();

    // fused gather: 64 rows x 64 float4 = 4096 / 256 threads
    const float4* w4 = (const float4*)w;
    float4* zq4 = (float4*)zq;
#pragma unroll
    for (int p = 0; p < 16; ++p) {
        int lin = p * 256 + tid;
        int row = lin >> 6, qq = lin & 63;
        zq4[(size_t)(rowblk + row) * 64 + qq] = w4[(size_t)widx_s[row] * 64 + qq];
    }
}

// ---------------------------------------------------------------------------
// Exact np-f32 rescore of compacted flagged rows (round-5-verified semantics;
// k4-outer/cc-inner, no spill — round 10/11 lesson).
// ---------------------------------------------------------------------------
__global__ __launch_bounds__(256) void rescue_kernel(
    const float* __restrict__ x, const float* __restrict__ w,
    const float* __restrict__ w2g, const int* __restrict__ flagcnt,
    const int* __restrict__ flaglist, float* __restrict__ zout,
    float* __restrict__ zq) {
    __shared__ __align__(16) float xs[DIM];
    __shared__ float dv[256];
    __shared__ int di[256];
    __shared__ int mi_s;
    __shared__ float x2_s;
    const int tid = threadIdx.x;
    const int cnt = flagcnt[0];
    for (int f = blockIdx.x; f < cnt; f += gridDim.x) {
        const int r = flaglist[f];
        __syncthreads();
        for (int i = tid; i < DIM; i += 256) xs[i] = x[(size_t)r * DIM + i];
        __syncthreads();
        if (tid == 0)
            x2_s = np_block128_sumsq(xs) + np_block128_sumsq(xs + 128);
        __syncthreads();
        const float x2vv = x2_s;
        const float4* xs4 = (const float4*)xs;
        const float4* wr0 = (const float4*)(w + (size_t)(tid + 0 * 256) * DIM);
        const float4* wr1 = (const float4*)(w + (size_t)(tid + 1 * 256) * DIM);
        const float4* wr2 = (const float4*)(w + (size_t)(tid + 2 * 256) * DIM);
        const float4* wr3 = (const float4*)(w + (size_t)(tid + 3 * 256) * DIM);
        float acc0 = 0.f, acc1 = 0.f, acc2 = 0.f, acc3 = 0.f;
#pragma unroll 4
        for (int k4 = 0; k4 < DIM / 4; ++k4) {
            float4 xv = xs4[k4];
            float4 w0 = wr0[k4], w1 = wr1[k4], w2 = wr2[k4], w3 = wr3[k4];
            acc0 = __builtin_fmaf(xv.x, w0.x, acc0);
            acc0 = __builtin_fmaf(xv.y, w0.y, acc0);
            acc0 = __builtin_fmaf(xv.z, w0.z, acc0);
            acc0 = __builtin_fmaf(xv.w, w0.w, acc0);
            acc1 = __builtin_fmaf(xv.x, w1.x, acc1);
            acc1 = __builtin_fmaf(xv.y, w1.y, acc1);
            acc1 = __builtin_fmaf(xv.z, w1.z, acc1);
            acc1 = __builtin_fmaf(xv.w, w1.w, acc1);
            acc2 = __builtin_fmaf(xv.x, w2.x, acc2);
            acc2 = __builtin_fmaf(xv.y, w2.y, acc2);
            acc2 = __builtin_fmaf(xv.z, w2.z, acc2);
            acc2 = __builtin_fmaf(xv.w, w2.w, acc2);
            acc3 = __builtin_fmaf(xv.x, w3.x, acc3);
            acc3 = __builtin_fmaf(xv.y, w3.y, acc3);
            acc3 = __builtin_fmaf(xv.z, w3.z, acc3);
            acc3 = __builtin_fmaf(xv.w, w3.w, acc3);
        }
        float bv = INFINITY;
        int bi = 0;
        float accs[4] = {acc0, acc1, acc2, acc3};
#pragma unroll
        for (int cc = 0; cc < 4; ++cc) {
            int c = tid + cc * 256;
            float s = (x2vv - 2.0f * accs[cc]) + w2g[c];
            if (s < bv) { bv = s; bi = c; }
        }
        dv[tid] = bv;
        di[tid] = bi;
        __syncthreads();
        if (tid == 0) {
            float mv = dv[0];
            int mi = di[0];
            for (int t = 1; t < 256; ++t)
                if (dv[t] < mv || (dv[t] == mv && di[t] < mi)) { mv = dv[t]; mi = di[t]; }
            zout[r] = (float)mi;
            mi_s = mi;
        }
        __syncthreads();
        zq[(size_t)r * DIM + tid] = w[(size_t)mi_s * DIM + tid];
    }
}

// ===========================================================================
// Fallback (round-5 passing LDS kernel) if ws is too small. Needs only x2/w2.
// ===========================================================================
#define BM 64
#define BN 128
#define BK 64
#define LDX 68

__global__ __launch_bounds__(256) void vq_kernel_lds(
    const float* __restrict__ x, const float* __restrict__ w,
    const float* __restrict__ x2g, const float* __restrict__ w2g,
    float* __restrict__ zout, float* __restrict__ zq) {
    __shared__ float xs[BM * LDX];
    __shared__ float ws_[BN * LDX];
    __shared__ float sw2[K_CODES];
    __shared__ float sx2[BM];
    __shared__ int widx[BM];

    const int tid = threadIdx.x;
    const int bm0 = blockIdx.x * BM;
    const int rg = tid & 15;
    const int cg = tid >> 4;

    for (int i = tid; i < K_CODES; i += 256) sw2[i] = w2g[i];
    if (tid < BM) sx2[tid] = x2g[bm0 + tid];

    float best[4];
    int bidx[4];
#pragma unroll
    for (int i = 0; i < 4; ++i) { best[i] = INFINITY; bidx[i] = 0; }

    const float4* x4 = (const float4*)x;
    const float4* w4 = (const float4*)w;

    for (int cn = 0; cn < K_CODES / BN; ++cn) {
        float acc[4][8];
#pragma unroll
        for (int i = 0; i < 4; ++i)
#pragma unroll
            for (int j = 0; j < 8; ++j) acc[i][j] = 0.f;

        for (int dk = 0; dk < DIM / BK; ++dk) {
            __syncthreads();
#pragma unroll
            for (int p = 0; p < 4; ++p) {
                int l = p * 256 + tid;
                int row = l >> 4, c4 = l & 15;
                float4 v = x4[(size_t)(bm0 + row) * (DIM / 4) + dk * (BK / 4) + c4];
                *(float4*)&xs[row * LDX + c4 * 4] = v;
            }
#pragma unroll
            for (int p = 0; p < 8; ++p) {
                int l = p * 256 + tid;
                int row = l >> 4, c4 = l & 15;
                float4 v = w4[(size_t)(cn * BN + row) * (DIM / 4) + dk * (BK / 4) + c4];
                *(float4*)&ws_[row * LDX + c4 * 4] = v;
            }
            __syncthreads();
#pragma unroll
            for (int d = 0; d < BK; d += 4) {
                float4 xv[4], wv[8];
#pragma unroll
                for (int i = 0; i < 4; ++i)
                    xv[i] = *(const float4*)&xs[(rg + 16 * i) * LDX + d];
#pragma unroll
                for (int j = 0; j < 8; ++j)
                    wv[j] = *(const float4*)&ws_[(cg + 16 * j) * LDX + d];
#pragma unroll
                for (int i = 0; i < 4; ++i)
#pragma unroll
                    for (int j = 0; j < 8; ++j) {
                        acc[i][j] = __builtin_fmaf(xv[i].x, wv[j].x, acc[i][j]);
                        acc[i][j] = __builtin_fmaf(xv[i].y, wv[j].y, acc[i][j]);
                        acc[i][j] = __builtin_fmaf(xv[i].z, wv[j].z, acc[i][j]);
                        acc[i][j] = __builtin_fmaf(xv[i].w, wv[j].w, acc[i][j]);
                    }
            }
        }
#pragma unroll
        for (int j = 0; j < 8; ++j) {
            int c = cn * BN + cg + 16 * j;
            float w2v = sw2[c];
#pragma unroll
            for (int i = 0; i < 4; ++i) {
                float t = sx2[rg + 16 * i] - 2.0f * acc[i][j];
                float s = t + w2v;
                if (s < best[i]) { best[i] = s; bidx[i] = c; }
            }
        }
    }

    __syncthreads();
    float* sval = xs;
    int* sidx = (int*)(xs + 64 * 17);
#pragma unroll
    for (int i = 0; i < 4; ++i) {
        sval[(rg + 16 * i) * 17 + cg] = best[i];
        sidx[(rg + 16 * i) * 17 + cg] = bidx[i];
    }
    __syncthreads();
    if (tid < BM) {
        float bv = INFINITY;
        int bi = 0;
        for (int c = 0; c < 16; ++c) {
            float v = sval[tid * 17 + c];
            int id = sidx[tid * 17 + c];
            if (v < bv || (v == bv && id < bi)) { bv = v; bi = id; }
        }
        widx[tid] = bi;
        zout[bm0 + tid] = (float)bi;
    }
    __syncthreads();
    float4* zq4 = (float4*)zq;
#pragma unroll
    for (int p = 0; p < 16; ++p) {
        int lin = p * 256 + tid;
        int row = lin >> 6, q = lin & 63;
        zq4[(size_t)(bm0 + row) * 64 + q] = w4[(size_t)widx[row] * 64 + q];
    }
}

extern "C" void kernel_launch(void* const* d_in, const int* in_sizes, int n_in,
                              void* d_out, int out_size, void* d_ws, size_t ws_size,
                              hipStream_t stream) {
    const float* z_e = (const float*)d_in[0];
    const float* emb = (const float*)d_in[1];
    float* x2g = (float*)d_ws;                                   // fallback x2
    int* flaglist = (int*)d_ws;                                  // MFMA path [32768]
    float* w2g = x2g + N_ROWS;                                   // [1024]
    unsigned short* wfrag = (unsigned short*)(w2g + K_CODES);    // [524288] = 1 MB
    int* flagcnt = (int*)(wfrag + (size_t)2 * K_CODES * DIM);    // [1]
    float* zout = (float*)d_out;                                 // [32768]
    float* zq = (float*)d_out + N_ROWS;                          // [32768*256]

    if (ws_size >= WS_NEEDED) {
        wprep_kernel<<<K_CODES / 16, 256, 0, stream>>>(emb, w2g, wfrag, flagcnt);
        vq_mfma<<<N_ROWS / 64, 256, 0, stream>>>(z_e, (const uint4*)wfrag, w2g,
                                                 emb, zout, zq, flagcnt, flaglist);
        rescue_kernel<<<256, 256, 0, stream>>>(z_e, emb, w2g, flagcnt,
                                               flaglist, zout, zq);
    } else {
        npsumsq_kernel<<<N_ROWS / 16, 64, 0, stream>>>(z_e, x2g);
        npsumsq_kernel<<<K_CODES / 16, 64, 0, stream>>>(emb, w2g);
        vq_kernel_lds<<<N_ROWS / BM, 256, 0, stream>>>(z_e, emb, x2g, w2g, zout, zq);
    }
}